// Round 1
// baseline (1148.405 us; speedup 1.0000x reference)
//
#include <hip/hip_runtime.h>
#include <math.h>

#define BATCH  2
#define SEQ    2048
#define DMODEL 1024
#define NH     16
#define HD     64
#define NQKV   3072            // 3*NH*HD
#define ROWS   (BATCH*SEQ)     // 4096
#define SCALE  0.125f          // 1/sqrt(64)

// ---------------------------------------------------------------------------
// NT GEMM: C[M,N] = A[M,K] * B[N,K]^T, all row-major (K contiguous in both).
// 128x128 tile, BK=16, 256 threads, 8x8 micro-tile per thread split as
// rows {ty*4+i, 64+ty*4+i}, cols {tx*4+j, 64+tx*4+j} so LDS reads are
// broadcast/2-way only (free on gfx950).
// ---------------------------------------------------------------------------
__global__ __launch_bounds__(256) void gemm_nt_128(
    const float* __restrict__ A, const float* __restrict__ Bm,
    float* __restrict__ C, int M, int N, int K)
{
    __shared__ float As[16][128];
    __shared__ float Bs[16][128];
    const int tid = threadIdx.x;
    const int tx = tid & 15;
    const int ty = tid >> 4;
    const int bm = blockIdx.x * 128;
    const int bn = blockIdx.y * 128;
    const int lr = tid >> 1;          // 0..127: tile row to load
    const int lk = (tid & 1) * 8;     // 0 or 8: k sub-offset

    float acc[8][8];
#pragma unroll
    for (int i = 0; i < 8; ++i)
#pragma unroll
        for (int j = 0; j < 8; ++j) acc[i][j] = 0.0f;

    const float* Arow = A  + (size_t)(bm + lr) * K + lk;
    const float* Brow = Bm + (size_t)(bn + lr) * K + lk;

    for (int k0 = 0; k0 < K; k0 += 16) {
        float4 a0 = *(const float4*)(Arow + k0);
        float4 a1 = *(const float4*)(Arow + k0 + 4);
        float4 b0 = *(const float4*)(Brow + k0);
        float4 b1 = *(const float4*)(Brow + k0 + 4);
        __syncthreads();   // previous iteration's reads done before overwrite
        As[lk+0][lr]=a0.x; As[lk+1][lr]=a0.y; As[lk+2][lr]=a0.z; As[lk+3][lr]=a0.w;
        As[lk+4][lr]=a1.x; As[lk+5][lr]=a1.y; As[lk+6][lr]=a1.z; As[lk+7][lr]=a1.w;
        Bs[lk+0][lr]=b0.x; Bs[lk+1][lr]=b0.y; Bs[lk+2][lr]=b0.z; Bs[lk+3][lr]=b0.w;
        Bs[lk+4][lr]=b1.x; Bs[lk+5][lr]=b1.y; Bs[lk+6][lr]=b1.z; Bs[lk+7][lr]=b1.w;
        __syncthreads();
#pragma unroll
        for (int kk = 0; kk < 16; ++kk) {
            float4 aL = *(const float4*)&As[kk][ty*4];
            float4 aH = *(const float4*)&As[kk][64 + ty*4];
            float4 bL = *(const float4*)&Bs[kk][tx*4];
            float4 bH = *(const float4*)&Bs[kk][64 + tx*4];
            float ar[8] = {aL.x,aL.y,aL.z,aL.w,aH.x,aH.y,aH.z,aH.w};
            float br[8] = {bL.x,bL.y,bL.z,bL.w,bH.x,bH.y,bH.z,bH.w};
#pragma unroll
            for (int i = 0; i < 8; ++i)
#pragma unroll
                for (int j = 0; j < 8; ++j)
                    acc[i][j] = fmaf(ar[i], br[j], acc[i][j]);
        }
    }
#pragma unroll
    for (int i = 0; i < 8; ++i) {
        int r = bm + ((i < 4) ? (ty*4 + i) : (64 + ty*4 + i - 4));
        float4 c0 = make_float4(acc[i][0], acc[i][1], acc[i][2], acc[i][3]);
        float4 c1 = make_float4(acc[i][4], acc[i][5], acc[i][6], acc[i][7]);
        *(float4*)(C + (size_t)r * N + bn + tx*4)      = c0;
        *(float4*)(C + (size_t)r * N + bn + 64 + tx*4) = c1;
    }
}

// ---------------------------------------------------------------------------
// In-place RoPE on the q (t=0) and k (t=1) slices of qkv[B*S][3][NH][HD].
// idx bits: i[0:5) h[5:9) t[9] s[10:21) b[21]
// ---------------------------------------------------------------------------
__global__ void rope_kernel(float* __restrict__ qkv, const float* __restrict__ freqs)
{
    int idx = blockIdx.x * 256 + threadIdx.x;
    int i = idx & 31;
    int h = (idx >> 5) & (NH - 1);
    int t = (idx >> 9) & 1;
    int s = (idx >> 10) & (SEQ - 1);
    int b = idx >> 21;
    float ang = (float)s * freqs[i];
    float sn, cs;
    sincosf(ang, &sn, &cs);            // accurate range reduction (args up to 2047)
    float* base = qkv + (size_t)(b * SEQ + s) * NQKV + t * (NH * HD) + h * HD;
    float x1 = base[i], x2 = base[i + 32];
    base[i]      = x1 * cs - x2 * sn;
    base[i + 32] = x1 * sn + x2 * cs;
}

// ---------------------------------------------------------------------------
// kb[h][d] = -max(p,0.01) * log1p(max(a,0.01) * d),  d = |q-k| in [0,SEQ)
// ---------------------------------------------------------------------------
__global__ void bias_table_kernel(const float* __restrict__ bias_p,
                                  const float* __restrict__ bias_a,
                                  float* __restrict__ kb)
{
    int idx = blockIdx.x * 256 + threadIdx.x;     // NH*SEQ total
    int h = idx >> 11;
    int d = idx & (SEQ - 1);
    float p = fmaxf(bias_p[h], 0.01f);
    float a = fmaxf(bias_a[h], 0.01f);
    kb[idx] = -p * log1pf(a * (float)d);
}

// ---------------------------------------------------------------------------
// Flash-style attention. One block = (b, h, 64-row q tile). 256 threads as
// 16x16: thread (ty,tx) owns score rows qi=ty*4+i, score cols kj=tx+16*j
// (strided cols -> conflict-free Ks/Vs access). Online softmax state per row
// replicated across the 16 tx lanes via __shfl_xor (row group is lane-aligned
// inside wave64). P round-trips through LDS (aliased onto Ks: 3x64x68 floats
// = 52 KB < 64 KB static limit).
// ---------------------------------------------------------------------------
__global__ __launch_bounds__(256) void attn_kernel(
    const float* __restrict__ qkv, const float* __restrict__ kb,
    float* __restrict__ attn_out)
{
    __shared__ float Qs[64][68];
    __shared__ float Ks[64][68];
    __shared__ float Vs[64][68];
    float (*Ps)[68] = Ks;              // reuse Ks storage for P

    const int tid = threadIdx.x;
    const int tx = tid & 15;
    const int ty = tid >> 4;
    const int q0 = blockIdx.x * 64;
    const int h  = blockIdx.y;
    const int b  = blockIdx.z;
    const float* kbh = kb + h * SEQ;

    {   // load Q tile (scaled): 4 threads per row, 16 floats each
        int r  = tid >> 2;
        int c0 = (tid & 3) * 16;
        const float* src = qkv + (size_t)(b * SEQ + q0 + r) * NQKV + h * HD + c0;
#pragma unroll
        for (int u = 0; u < 4; ++u) {
            float4 v = *(const float4*)(src + u * 4);
            Qs[r][c0 + u*4 + 0] = v.x * SCALE;
            Qs[r][c0 + u*4 + 1] = v.y * SCALE;
            Qs[r][c0 + u*4 + 2] = v.z * SCALE;
            Qs[r][c0 + u*4 + 3] = v.w * SCALE;
        }
    }

    float m_i[4], l_i[4], o[4][4];
#pragma unroll
    for (int i = 0; i < 4; ++i) {
        m_i[i] = -INFINITY; l_i[i] = 0.0f;
#pragma unroll
        for (int j = 0; j < 4; ++j) o[i][j] = 0.0f;
    }

    for (int kt = 0; kt < SEQ / 64; ++kt) {
        const int k0 = kt * 64;
        __syncthreads();               // previous iter's Ps/Vs reads complete
        {   // load K and V tiles
            int r  = tid >> 2;
            int c0 = (tid & 3) * 16;
            const float* src = qkv + (size_t)(b * SEQ + k0 + r) * NQKV + h * HD + c0;
#pragma unroll
            for (int u = 0; u < 4; ++u) {
                float4 kv = *(const float4*)(src + (NH*HD) + u * 4);
                Ks[r][c0 + u*4 + 0] = kv.x; Ks[r][c0 + u*4 + 1] = kv.y;
                Ks[r][c0 + u*4 + 2] = kv.z; Ks[r][c0 + u*4 + 3] = kv.w;
                float4 vv = *(const float4*)(src + 2*(NH*HD) + u * 4);
                Vs[r][c0 + u*4 + 0] = vv.x; Vs[r][c0 + u*4 + 1] = vv.y;
                Vs[r][c0 + u*4 + 2] = vv.z; Vs[r][c0 + u*4 + 3] = vv.w;
            }
        }
        __syncthreads();

        // ---- scores: 4x4 per thread, dot over d=64 in float4 steps ----
        float sc[4][4];
#pragma unroll
        for (int i = 0; i < 4; ++i)
#pragma unroll
            for (int j = 0; j < 4; ++j) sc[i][j] = 0.0f;
#pragma unroll
        for (int d = 0; d < 64; d += 4) {
            float4 qv[4], kv[4];
#pragma unroll
            for (int i = 0; i < 4; ++i) qv[i] = *(const float4*)&Qs[ty*4 + i][d];
#pragma unroll
            for (int j = 0; j < 4; ++j) kv[j] = *(const float4*)&Ks[tx + 16*j][d];
#pragma unroll
            for (int i = 0; i < 4; ++i)
#pragma unroll
                for (int j = 0; j < 4; ++j)
                    sc[i][j] += qv[i].x*kv[j].x + qv[i].y*kv[j].y
                              + qv[i].z*kv[j].z + qv[i].w*kv[j].w;
        }
        __syncthreads();               // all Ks reads done (Ps aliases Ks)

        // ---- bias + online softmax ----
        float alpha[4], rsum[4];
#pragma unroll
        for (int i = 0; i < 4; ++i) {
            float mm = -INFINITY;
#pragma unroll
            for (int j = 0; j < 4; ++j) {
                int dd = (q0 + ty*4 + i) - (k0 + tx + 16*j);
                if (dd < 0) dd = -dd;
                sc[i][j] += kbh[dd];
                mm = fmaxf(mm, sc[i][j]);
            }
#pragma unroll
            for (int off = 1; off < 16; off <<= 1)
                mm = fmaxf(mm, __shfl_xor(mm, off));
            float mn = fmaxf(m_i[i], mm);
            alpha[i] = __expf(m_i[i] - mn);
            m_i[i] = mn;
            float s = 0.0f;
#pragma unroll
            for (int j = 0; j < 4; ++j) {
                float e = __expf(sc[i][j] - mn);
                Ps[ty*4 + i][tx + 16*j] = e;
                s += e;
            }
            rsum[i] = s;
        }
#pragma unroll
        for (int i = 0; i < 4; ++i) {
#pragma unroll
            for (int off = 1; off < 16; off <<= 1)
                rsum[i] += __shfl_xor(rsum[i], off);
            l_i[i] = l_i[i] * alpha[i] + rsum[i];
#pragma unroll
            for (int j = 0; j < 4; ++j) o[i][j] *= alpha[i];
        }
        __syncthreads();               // Ps fully written

        // ---- PV: o[i][j] += sum_k P[qi][k] * V[k][dj] ----
#pragma unroll 4
        for (int k = 0; k < 64; ++k) {
            float pr[4], vr[4];
#pragma unroll
            for (int i = 0; i < 4; ++i) pr[i] = Ps[ty*4 + i][k];
#pragma unroll
            for (int j = 0; j < 4; ++j) vr[j] = Vs[k][tx + 16*j];
#pragma unroll
            for (int i = 0; i < 4; ++i)
#pragma unroll
                for (int j = 0; j < 4; ++j)
                    o[i][j] = fmaf(pr[i], vr[j], o[i][j]);
        }
    }

    // ---- epilogue: normalize and store [B,S,H*D] ----
#pragma unroll
    for (int i = 0; i < 4; ++i) {
        float inv = 1.0f / l_i[i];
        float* dst = attn_out + (size_t)(b * SEQ + q0 + ty*4 + i) * DMODEL + h * HD;
#pragma unroll
        for (int j = 0; j < 4; ++j) dst[tx + 16*j] = o[i][j] * inv;
    }
}

// ---------------------------------------------------------------------------
extern "C" void kernel_launch(void* const* d_in, const int* in_sizes, int n_in,
                              void* d_out, int out_size, void* d_ws, size_t ws_size,
                              hipStream_t stream)
{
    (void)in_sizes; (void)n_in; (void)out_size; (void)ws_size;
    const float* x      = (const float*)d_in[0];
    const float* qkv_w  = (const float*)d_in[1];
    const float* out_w  = (const float*)d_in[2];
    const float* bias_p = (const float*)d_in[3];
    const float* bias_a = (const float*)d_in[4];
    const float* freqs  = (const float*)d_in[5];
    float* out = (float*)d_out;

    // workspace layout (fp32): qkv [4096][3072] | attn [4096][1024] | kb [16][2048]
    float* qkv  = (float*)d_ws;
    float* attn = qkv + (size_t)ROWS * NQKV;
    float* kb   = attn + (size_t)ROWS * DMODEL;

    // 1) QKV projection: qkv[m,n] = sum_k x[m,k] * qkv_w[n,k]
    gemm_nt_128<<<dim3(ROWS/128, NQKV/128), 256, 0, stream>>>(x, qkv_w, qkv, ROWS, NQKV, DMODEL);
    // 2) RoPE in place on q,k
    rope_kernel<<<dim3((BATCH*SEQ*2*NH*32)/256), 256, 0, stream>>>(qkv, freqs);
    // 3) distance-bias table
    bias_table_kernel<<<dim3(NH*SEQ/256), 256, 0, stream>>>(bias_p, bias_a, kb);
    // 4) attention
    attn_kernel<<<dim3(SEQ/64, NH, BATCH), 256, 0, stream>>>(qkv, kb, attn);
    // 5) output projection: out[m,n] = sum_k attn[m,k] * out_w[n,k]
    gemm_nt_128<<<dim3(ROWS/128, DMODEL/128), 256, 0, stream>>>(attn, out_w, out, ROWS, DMODEL, DMODEL);
}

// Round 2
// 307.075 us; speedup vs baseline: 3.7398x; 3.7398x over previous
//
#include <hip/hip_runtime.h>
#include <math.h>

#define BATCH  2
#define SEQ    2048
#define DMODEL 1024
#define NH     16
#define HD     64
#define NQKV   3072
#define ROWS   (BATCH*SEQ)

typedef unsigned short u16;
typedef __bf16 bf16x8 __attribute__((ext_vector_type(8)));
typedef float  f32x4  __attribute__((ext_vector_type(4)));

__device__ __forceinline__ u16 f2bf(float f) {          // RNE f32->bf16
    unsigned int u = __float_as_uint(f);
    u += 0x7FFFu + ((u >> 16) & 1u);
    return (u16)(u >> 16);
}
__device__ __forceinline__ float bf2f(u16 v) {
    return __uint_as_float(((unsigned int)v) << 16);
}

// ---------------------------------------------------------------------------
// elementwise f32 -> bf16 (n multiple of 4)
// ---------------------------------------------------------------------------
__global__ void f2bf_kernel(const float* __restrict__ in, u16* __restrict__ out, int n)
{
    int i = (blockIdx.x * 256 + threadIdx.x) * 4;
    if (i >= n) return;
    float4 v = *(const float4*)(in + i);
    u16 o[4] = { f2bf(v.x), f2bf(v.y), f2bf(v.z), f2bf(v.w) };
    *(uint2*)(out + i) = *(const uint2*)o;
}

// ---------------------------------------------------------------------------
// kb[h][d] = -max(p,.01)*log1p(max(a,.01)*d)
// ---------------------------------------------------------------------------
__global__ void bias_table_kernel(const float* __restrict__ bias_p,
                                  const float* __restrict__ bias_a,
                                  float* __restrict__ kb)
{
    int idx = blockIdx.x * 256 + threadIdx.x;
    int h = idx >> 11;
    int d = idx & (SEQ - 1);
    float p = fmaxf(bias_p[h], 0.01f);
    float a = fmaxf(bias_a[h], 0.01f);
    kb[idx] = -p * log1pf(a * (float)d);
}

// ---------------------------------------------------------------------------
// bf16 NT GEMM: C[M,N] = A[M,K] * B[N,K]^T. 128x128 tile, BK=32, 4 waves,
// each wave a 64x64 quadrant as 4x4 grid of 16x16x32 MFMAs, fp32 accum.
// LDS row stride 40 bf16 (=80B, 16B-aligned, 2-way bank alias only on frags).
// ---------------------------------------------------------------------------
template<bool BF16OUT>
__global__ __launch_bounds__(256) void gemm_bf16(
    const u16* __restrict__ A, const u16* __restrict__ B,
    void* __restrict__ Cout, int M, int N, int K)
{
    __shared__ __align__(16) u16 As[128][40];
    __shared__ __align__(16) u16 Bs[128][40];
    const int tid  = threadIdx.x;
    const int wave = tid >> 6, lane = tid & 63;
    const int quad = lane >> 4, l16 = lane & 15;
    const int wrow = (wave >> 1) * 64, wcol = (wave & 1) * 64;
    const int bm = blockIdx.x * 128, bn = blockIdx.y * 128;
    const int lr = tid >> 1, lc = (tid & 1) * 16;

    f32x4 acc[4][4];
#pragma unroll
    for (int i = 0; i < 4; ++i)
#pragma unroll
        for (int j = 0; j < 4; ++j) acc[i][j] = (f32x4){0.f,0.f,0.f,0.f};

    const u16* Ag = A + (size_t)(bm + lr) * K + lc;
    const u16* Bg = B + (size_t)(bn + lr) * K + lc;

    for (int k0 = 0; k0 < K; k0 += 32) {
        uint4 a0 = *(const uint4*)(Ag + k0);
        uint4 a1 = *(const uint4*)(Ag + k0 + 8);
        uint4 b0 = *(const uint4*)(Bg + k0);
        uint4 b1 = *(const uint4*)(Bg + k0 + 8);
        __syncthreads();
        *(uint4*)&As[lr][lc]     = a0;
        *(uint4*)&As[lr][lc + 8] = a1;
        *(uint4*)&Bs[lr][lc]     = b0;
        *(uint4*)&Bs[lr][lc + 8] = b1;
        __syncthreads();
        bf16x8 af[4], bfr[4];
#pragma unroll
        for (int i = 0; i < 4; ++i)
            af[i] = *(const bf16x8*)&As[wrow + i*16 + l16][quad*8];
#pragma unroll
        for (int j = 0; j < 4; ++j)
            bfr[j] = *(const bf16x8*)&Bs[wcol + j*16 + l16][quad*8];
#pragma unroll
        for (int i = 0; i < 4; ++i)
#pragma unroll
            for (int j = 0; j < 4; ++j)
                acc[i][j] = __builtin_amdgcn_mfma_f32_16x16x32_bf16(af[i], bfr[j], acc[i][j], 0, 0, 0);
    }

#pragma unroll
    for (int i = 0; i < 4; ++i)
#pragma unroll
        for (int j = 0; j < 4; ++j) {
            int col = bn + wcol + j*16 + l16;
#pragma unroll
            for (int r = 0; r < 4; ++r) {
                int row = bm + wrow + i*16 + quad*4 + r;
                if (BF16OUT) ((u16*)Cout)[(size_t)row * N + col] = f2bf(acc[i][j][r]);
                else         ((float*)Cout)[(size_t)row * N + col] = acc[i][j][r];
            }
        }
}

// ---------------------------------------------------------------------------
// RoPE + layout conversion. Reads qkv_bf [B*S][3][NH][HD]; writes
// Qb[b][h][s][d] (rope, pre-scaled 0.125), Kb[b][h][s][d] (rope),
// Vt[b][h][d][s] (transposed for PV B-operand).
// block 256 = 4 waves; blockIdx.x = b*S+s, blockIdx.y = head group of 4.
// lane = d; rope pair (d, d^32) via shfl_xor.
// ---------------------------------------------------------------------------
__global__ __launch_bounds__(256) void qkv_convert(
    const u16* __restrict__ qkv_bf, const float* __restrict__ freqs,
    u16* __restrict__ Qb, u16* __restrict__ Kb, u16* __restrict__ Vt)
{
    const int bs = blockIdx.x;
    const int b = bs >> 11, s = bs & (SEQ - 1);
    const int wave = threadIdx.x >> 6, lane = threadIdx.x & 63;
    const int h = blockIdx.y * 4 + wave;
    const u16* base = qkv_bf + (size_t)bs * NQKV + h * HD + lane;
    float q = bf2f(base[0]);
    float k = bf2f(base[NH * HD]);
    float v = bf2f(base[2 * NH * HD]);
    float ang = (float)s * freqs[lane & 31];
    float sn, cs;
    sincosf(ang, &sn, &cs);
    float qo = __shfl_xor(q, 32);
    float ko = __shfl_xor(k, 32);
    float qr = (lane < 32) ? (q * cs - qo * sn) : (qo * sn + q * cs);
    float kr = (lane < 32) ? (k * cs - ko * sn) : (ko * sn + k * cs);
    size_t hb = (size_t)(b * NH + h) * SEQ * HD;
    Qb[hb + (size_t)s * HD + lane] = f2bf(qr * 0.125f);
    Kb[hb + (size_t)s * HD + lane] = f2bf(kr);
    Vt[hb + (size_t)lane * SEQ + s] = f2bf(v);
}

// ---------------------------------------------------------------------------
// MFMA flash attention. Block = (q-tile of 64, h, b); 4 waves, wave w owns
// q rows q0+w*16..+15. Q-frags from global (registers). Per 64-key tile:
// stage Ks[key][d], Vs[d][key] (pre-transposed global), bias slice (128 f32);
// QK^T (8 MFMA/wave) -> C-layout scores; bias+online softmax (16-lane shfl
// reductions); P -> per-wave LDS region [q][key] as bf16; PV (8 MFMA/wave).
// Output written directly as bf16 [B,S,H*D] for the out-projection GEMM.
// ---------------------------------------------------------------------------
__global__ __launch_bounds__(256) void attn_mfma(
    const u16* __restrict__ Qb, const u16* __restrict__ Kb,
    const u16* __restrict__ Vt, const float* __restrict__ kbt,
    u16* __restrict__ attn_bf)
{
    __shared__ __align__(16) u16 Ks[64][72];
    __shared__ __align__(16) u16 Vs[64][72];   // Vs[d][key]
    __shared__ __align__(16) u16 Ps[64][72];   // wave w: rows w*16..w*16+15
    __shared__ float bs_[128];

    const int tid = threadIdx.x;
    const int wave = tid >> 6, lane = tid & 63;
    const int quad = lane >> 4, l16 = lane & 15;
    const int q0 = blockIdx.x * 64, h = blockIdx.y, b = blockIdx.z;

    const u16* Qh = Qb + (size_t)(b * NH + h) * SEQ * HD;
    const u16* Kh = Kb + (size_t)(b * NH + h) * SEQ * HD;
    const u16* Vh = Vt + (size_t)(b * NH + h) * HD * SEQ;
    const float* kbh = kbt + h * SEQ;

    const int qrow = q0 + wave * 16 + l16;
    const bf16x8 qf0 = *(const bf16x8*)(Qh + (size_t)qrow * HD + quad * 8);
    const bf16x8 qf1 = *(const bf16x8*)(Qh + (size_t)qrow * HD + 32 + quad * 8);

    float m_i[4], l_i[4];
    f32x4 o[4];
#pragma unroll
    for (int r = 0; r < 4; ++r) { m_i[r] = -INFINITY; l_i[r] = 0.f; }
#pragma unroll
    for (int j = 0; j < 4; ++j) o[j] = (f32x4){0.f,0.f,0.f,0.f};

    const int r4 = tid >> 2, c16 = (tid & 3) * 16;

    for (int kt = 0; kt < SEQ / 64; ++kt) {
        const int k0 = kt * 64;
        __syncthreads();                       // prior iter PV reads done
        {
            const u16* ksrc = Kh + (size_t)(k0 + r4) * HD + c16;
            *(uint4*)&Ks[r4][c16]     = *(const uint4*)ksrc;
            *(uint4*)&Ks[r4][c16 + 8] = *(const uint4*)(ksrc + 8);
            const u16* vsrc = Vh + (size_t)r4 * SEQ + k0 + c16;
            *(uint4*)&Vs[r4][c16]     = *(const uint4*)vsrc;
            *(uint4*)&Vs[r4][c16 + 8] = *(const uint4*)(vsrc + 8);
        }
        int dq = q0 - k0; if (dq < 0) dq = -dq;
        const int lo = (dq <= 63) ? 0 : dq - 63;
        if (tid < 128) {
            int idx = lo + tid;
            bs_[tid] = kbh[idx < SEQ ? idx : SEQ - 1];
        }
        __syncthreads();

        // ---- scores ----
        f32x4 sc[4];
#pragma unroll
        for (int j = 0; j < 4; ++j) {
            bf16x8 kf0 = *(const bf16x8*)&Ks[j*16 + l16][quad*8];
            bf16x8 kf1 = *(const bf16x8*)&Ks[j*16 + l16][32 + quad*8];
            f32x4 z = (f32x4){0.f,0.f,0.f,0.f};
            z = __builtin_amdgcn_mfma_f32_16x16x32_bf16(qf0, kf0, z, 0, 0, 0);
            sc[j] = __builtin_amdgcn_mfma_f32_16x16x32_bf16(qf1, kf1, z, 0, 0, 0);
        }

        // ---- bias + online softmax (rows quad*4+r; cols spread on 16 lanes)
#pragma unroll
        for (int r = 0; r < 4; ++r) {
            int qidx = q0 + wave * 16 + quad * 4 + r;
            float mx = -INFINITY;
#pragma unroll
            for (int j = 0; j < 4; ++j) {
                int kidx = k0 + j * 16 + l16;
                int dist = qidx - kidx; if (dist < 0) dist = -dist;
                float vv = sc[j][r] + bs_[dist - lo];
                sc[j][r] = vv;
                mx = fmaxf(mx, vv);
            }
#pragma unroll
            for (int off = 1; off < 16; off <<= 1)
                mx = fmaxf(mx, __shfl_xor(mx, off));
            float mn = fmaxf(m_i[r], mx);
            float al = __expf(m_i[r] - mn);
            m_i[r] = mn;
            float s = 0.f;
#pragma unroll
            for (int j = 0; j < 4; ++j) {
                float e = __expf(sc[j][r] - mn);
                s += e;
                Ps[wave*16 + quad*4 + r][j*16 + l16] = f2bf(e);
            }
#pragma unroll
            for (int off = 1; off < 16; off <<= 1)
                s += __shfl_xor(s, off);
            l_i[r] = l_i[r] * al + s;
#pragma unroll
            for (int j = 0; j < 4; ++j) o[j][r] *= al;
        }
        // Ps is wave-private; same-wave DS ordering + compiler lgkmcnt
        // make the write->read safe without a barrier.

        // ---- PV ----
        bf16x8 pf0 = *(const bf16x8*)&Ps[wave*16 + l16][quad*8];
        bf16x8 pf1 = *(const bf16x8*)&Ps[wave*16 + l16][32 + quad*8];
#pragma unroll
        for (int j = 0; j < 4; ++j) {
            bf16x8 vf0 = *(const bf16x8*)&Vs[j*16 + l16][quad*8];
            bf16x8 vf1 = *(const bf16x8*)&Vs[j*16 + l16][32 + quad*8];
            o[j] = __builtin_amdgcn_mfma_f32_16x16x32_bf16(pf0, vf0, o[j], 0, 0, 0);
            o[j] = __builtin_amdgcn_mfma_f32_16x16x32_bf16(pf1, vf1, o[j], 0, 0, 0);
        }
    }

    // ---- epilogue: normalize, store bf16 [B,S,H*D] ----
#pragma unroll
    for (int r = 0; r < 4; ++r) {
        float inv = 1.0f / l_i[r];
        int row = q0 + wave * 16 + quad * 4 + r;
        u16* dst = attn_bf + (size_t)(b * SEQ + row) * DMODEL + h * HD;
#pragma unroll
        for (int j = 0; j < 4; ++j)
            dst[j*16 + l16] = f2bf(o[j][r] * inv);
    }
}

// ---------------------------------------------------------------------------
extern "C" void kernel_launch(void* const* d_in, const int* in_sizes, int n_in,
                              void* d_out, int out_size, void* d_ws, size_t ws_size,
                              hipStream_t stream)
{
    (void)in_sizes; (void)n_in; (void)out_size; (void)ws_size;
    const float* x      = (const float*)d_in[0];
    const float* qkv_w  = (const float*)d_in[1];
    const float* out_w  = (const float*)d_in[2];
    const float* bias_p = (const float*)d_in[3];
    const float* bias_a = (const float*)d_in[4];
    const float* freqs  = (const float*)d_in[5];
    float* out = (float*)d_out;

    // ws layout (bytes):
    //   [0, 24M)      qkv_bf  [4096][3072] bf16   (attn_bf aliases [0,8M))
    //   [24M, 32M)    x_bf    [4096][1024] bf16   (Qb aliases after gemm1)
    //   [32M, 38M)    w1_bf   [3072][1024] bf16
    //   [38M, 40M)    w2_bf   [1024][1024] bf16
    //   [40M, 48M)    Kb      [2][16][2048][64] bf16
    //   [48M, 56M)    Vt      [2][16][64][2048] bf16
    //   [56M, +128K)  kbt     [16][2048] f32
    char* ws = (char*)d_ws;
    u16*   qkv_bf  = (u16*)ws;
    u16*   attn_bf = (u16*)ws;
    u16*   x_bf    = (u16*)(ws + 25165824);
    u16*   Qb      = x_bf;
    u16*   w1_bf   = (u16*)(ws + 33554432);
    u16*   w2_bf   = (u16*)(ws + 39845888);
    u16*   Kb      = (u16*)(ws + 41943040);
    u16*   Vt      = (u16*)(ws + 50331648);
    float* kbt     = (float*)(ws + 58720256);

    f2bf_kernel<<<dim3(ROWS*DMODEL/1024), 256, 0, stream>>>(x, x_bf, ROWS*DMODEL);
    f2bf_kernel<<<dim3(NQKV*DMODEL/1024), 256, 0, stream>>>(qkv_w, w1_bf, NQKV*DMODEL);
    f2bf_kernel<<<dim3(DMODEL*DMODEL/1024), 256, 0, stream>>>(out_w, w2_bf, DMODEL*DMODEL);
    bias_table_kernel<<<dim3(NH*SEQ/256), 256, 0, stream>>>(bias_p, bias_a, kbt);

    gemm_bf16<true><<<dim3(ROWS/128, NQKV/128), 256, 0, stream>>>(x_bf, w1_bf, qkv_bf, ROWS, NQKV, DMODEL);
    qkv_convert<<<dim3(ROWS, NH/4), 256, 0, stream>>>(qkv_bf, freqs, Qb, Kb, Vt);
    attn_mfma<<<dim3(SEQ/64, NH, BATCH), 256, 0, stream>>>(Qb, Kb, Vt, kbt, attn_bf);
    gemm_bf16<false><<<dim3(ROWS/128, DMODEL/128), 256, 0, stream>>>(attn_bf, w2_bf, out, ROWS, DMODEL, DMODEL);
}

// Round 3
// 248.299 us; speedup vs baseline: 4.6251x; 1.2367x over previous
//
#include <hip/hip_runtime.h>
#include <math.h>

#define BATCH  2
#define SEQ    2048
#define DMODEL 1024
#define NH     16
#define HD     64
#define NQKV   3072
#define ROWS   (BATCH*SEQ)

typedef unsigned short u16;
typedef __bf16 bf16x8 __attribute__((ext_vector_type(8)));
typedef float  f32x4  __attribute__((ext_vector_type(4)));

typedef const __attribute__((address_space(1))) void* gptr_t;
typedef __attribute__((address_space(3))) void* lptr_t;

// async 16B/lane global->LDS: lds dest = wave-uniform base + lane*16
__device__ __forceinline__ void gload16(lptr_t l, const void* g) {
    __builtin_amdgcn_global_load_lds((gptr_t)g, l, 16, 0, 0);
}

__device__ __forceinline__ u16 f2bf(float f) {          // RNE f32->bf16
    unsigned int u = __float_as_uint(f);
    u += 0x7FFFu + ((u >> 16) & 1u);
    return (u16)(u >> 16);
}
__device__ __forceinline__ float bf2f(u16 v) {
    return __uint_as_float(((unsigned int)v) << 16);
}

// ---------------------------------------------------------------------------
__global__ void f2bf_kernel(const float* __restrict__ in, u16* __restrict__ out, int n)
{
    int i = (blockIdx.x * 256 + threadIdx.x) * 4;
    if (i >= n) return;
    float4 v = *(const float4*)(in + i);
    u16 o[4] = { f2bf(v.x), f2bf(v.y), f2bf(v.z), f2bf(v.w) };
    *(uint2*)(out + i) = *(const uint2*)o;
}

// ---------------------------------------------------------------------------
__global__ void bias_table_kernel(const float* __restrict__ bias_p,
                                  const float* __restrict__ bias_a,
                                  float* __restrict__ kb)
{
    int idx = blockIdx.x * 256 + threadIdx.x;
    int h = idx >> 11;
    int d = idx & (SEQ - 1);
    float p = fmaxf(bias_p[h], 0.01f);
    float a = fmaxf(bias_a[h], 0.01f);
    kb[idx] = -p * log1pf(a * (float)d);
}

// cs_tab[(s*32+d)*2] = cos(s*freqs[d]), +1 = sin
__global__ void rope_table_kernel(const float* __restrict__ freqs, float* __restrict__ tab)
{
    int idx = blockIdx.x * 256 + threadIdx.x;   // SEQ*32
    int s = idx >> 5, d = idx & 31;
    float sn, cs;
    sincosf((float)s * freqs[d], &sn, &cs);
    tab[idx * 2]     = cs;
    tab[idx * 2 + 1] = sn;
}

// ---------------------------------------------------------------------------
// bf16 NT GEMM, m97-style: 128x128 tile, BK=32, global_load_lds staging with
// XOR chunk swizzle (chunk' = chunk ^ (row&3), chunk = 8 u16 = 16B).
// ---------------------------------------------------------------------------
template<bool BF16OUT>
__global__ __launch_bounds__(256) void gemm_bf16(
    const u16* __restrict__ A, const u16* __restrict__ B,
    void* __restrict__ Cout, int M, int N, int K)
{
    __shared__ __align__(16) u16 As[128][32];
    __shared__ __align__(16) u16 Bs[128][32];
    const int tid  = threadIdx.x;
    const int wave = tid >> 6, lane = tid & 63;
    const int quad = lane >> 4, l16 = lane & 15;
    const int wrow = (wave >> 1) * 64, wcol = (wave & 1) * 64;
    const int bm = blockIdx.x * 128, bn = blockIdx.y * 128;

    // staging: per issue a wave covers 16 rows x 4 chunks; lane -> (row,chunk')
    const int srow = lane >> 2;                       // 0..15
    const int scol = ((lane & 3) ^ (srow & 3)) * 8;   // swizzled global chunk (u16)
    // frag read swizzle: row&3 == l16&3
    const int fsw = (quad ^ (l16 & 3)) * 8;

    f32x4 acc[4][4];
#pragma unroll
    for (int i = 0; i < 4; ++i)
#pragma unroll
        for (int j = 0; j < 4; ++j) acc[i][j] = (f32x4){0.f,0.f,0.f,0.f};

    const u16* Ag0 = A + (size_t)(bm + wave*32 + srow)      * K + scol;
    const u16* Ag1 = A + (size_t)(bm + wave*32 + 16 + srow) * K + scol;
    const u16* Bg0 = B + (size_t)(bn + wave*32 + srow)      * K + scol;
    const u16* Bg1 = B + (size_t)(bn + wave*32 + 16 + srow) * K + scol;

    for (int k0 = 0; k0 < K; k0 += 32) {
        __syncthreads();
        gload16((lptr_t)&As[wave*32][0],      Ag0 + k0);
        gload16((lptr_t)&As[wave*32 + 16][0], Ag1 + k0);
        gload16((lptr_t)&Bs[wave*32][0],      Bg0 + k0);
        gload16((lptr_t)&Bs[wave*32 + 16][0], Bg1 + k0);
        __syncthreads();
        bf16x8 af[4], bfr[4];
#pragma unroll
        for (int i = 0; i < 4; ++i)
            af[i] = *(const bf16x8*)&As[wrow + i*16 + l16][fsw];
#pragma unroll
        for (int j = 0; j < 4; ++j)
            bfr[j] = *(const bf16x8*)&Bs[wcol + j*16 + l16][fsw];
#pragma unroll
        for (int i = 0; i < 4; ++i)
#pragma unroll
            for (int j = 0; j < 4; ++j)
                acc[i][j] = __builtin_amdgcn_mfma_f32_16x16x32_bf16(af[i], bfr[j], acc[i][j], 0, 0, 0);
    }

#pragma unroll
    for (int i = 0; i < 4; ++i)
#pragma unroll
        for (int j = 0; j < 4; ++j) {
            int col = bn + wcol + j*16 + l16;
#pragma unroll
            for (int r = 0; r < 4; ++r) {
                int row = bm + wrow + i*16 + quad*4 + r;
                if (BF16OUT) ((u16*)Cout)[(size_t)row * N + col] = f2bf(acc[i][j][r]);
                else         ((float*)Cout)[(size_t)row * N + col] = acc[i][j][r];
            }
        }
}

// ---------------------------------------------------------------------------
// RoPE (table-based) + layout conversion, tiled. Block = (64 s-rows, h, b).
// Writes Qb[b][h][s][d] (scaled 0.125), Kb[b][h][s][d], Vt[b][h][d][s].
// ---------------------------------------------------------------------------
__global__ __launch_bounds__(256) void qkv_convert(
    const u16* __restrict__ qkv_bf, const float* __restrict__ cs_tab,
    u16* __restrict__ Qb, u16* __restrict__ Kb, u16* __restrict__ Vt)
{
    __shared__ __align__(16) u16 Vtile[64][72];
    const int tid = threadIdx.x;
    const int r = tid >> 2, c = tid & 3;
    const int s0 = blockIdx.x * 64, h = blockIdx.y, b = blockIdx.z;
    const int s = s0 + r;
    const u16* src = qkv_bf + (size_t)(b * SEQ + s) * NQKV + h * HD;
    const size_t hb = (size_t)(b * NH + h) * SEQ * HD;

    // V -> LDS
    *(uint4*)&Vtile[r][c*16]     = *(const uint4*)(src + 2*NH*HD + c*16);
    *(uint4*)&Vtile[r][c*16 + 8] = *(const uint4*)(src + 2*NH*HD + c*16 + 8);

    // rope: c<2 -> Q halves, c>=2 -> K halves
    {
        const u16* m = src + ((c < 2) ? 0 : NH*HD);
        const int d1 = (c & 1) * 16;
        u16 x1[16], x2[16];
        *(uint4*)&x1[0] = *(const uint4*)(m + d1);
        *(uint4*)&x1[8] = *(const uint4*)(m + d1 + 8);
        *(uint4*)&x2[0] = *(const uint4*)(m + d1 + 32);
        *(uint4*)&x2[8] = *(const uint4*)(m + d1 + 40);
        const float* ct = cs_tab + ((size_t)s * 32 + d1) * 2;
        const float sc = (c < 2) ? 0.125f : 1.0f;
        u16 y1[16], y2[16];
#pragma unroll
        for (int u = 0; u < 16; ++u) {
            float cs = ct[u*2], sn = ct[u*2 + 1];
            float a = bf2f(x1[u]), bq = bf2f(x2[u]);
            y1[u] = f2bf((a * cs - bq * sn) * sc);
            y2[u] = f2bf((a * sn + bq * cs) * sc);
        }
        u16* dst = ((c < 2) ? Qb : Kb) + hb + (size_t)s * HD + d1;
        *(uint4*)(dst)      = *(const uint4*)&y1[0];
        *(uint4*)(dst + 8)  = *(const uint4*)&y1[8];
        *(uint4*)(dst + 32) = *(const uint4*)&y2[0];
        *(uint4*)(dst + 40) = *(const uint4*)&y2[8];
    }
    __syncthreads();

    // Vt[d][s]: thread -> d-row r, keys c*16..+15
    u16 vv[16];
#pragma unroll
    for (int u = 0; u < 16; ++u) vv[u] = Vtile[c*16 + u][r];
    u16* dst = Vt + hb + (size_t)r * SEQ + s0 + c*16;
    *(uint4*)(dst)     = *(const uint4*)&vv[0];
    *(uint4*)(dst + 8) = *(const uint4*)&vv[8];
}

// ---------------------------------------------------------------------------
// MFMA flash attention, fixed-max softmax (max=0 is safe: |score| < ~4,
// bias <= 0 => exp in (0, ~60), fp32 sum can't overflow at S=2048).
// global_load_lds staging with XOR chunk swizzle (chunk' = chunk^(row&7)).
// ---------------------------------------------------------------------------
__global__ __launch_bounds__(256) void attn_mfma(
    const u16* __restrict__ Qb, const u16* __restrict__ Kb,
    const u16* __restrict__ Vt, const float* __restrict__ kbt,
    u16* __restrict__ attn_bf)
{
    __shared__ __align__(16) u16 Ks[64][64];   // [key][d], swizzled chunks
    __shared__ __align__(16) u16 Vs[64][64];   // [d][key], swizzled chunks
    __shared__ __align__(16) u16 Ps[64][72];   // per-wave rows, padded
    __shared__ float bs_[128];

    const int tid = threadIdx.x;
    const int wave = tid >> 6, lane = tid & 63;
    const int quad = lane >> 4, l16 = lane & 15;
    const int q0 = blockIdx.x * 64, h = blockIdx.y, b = blockIdx.z;

    const u16* Qh = Qb + (size_t)(b * NH + h) * SEQ * HD;
    const u16* Kh = Kb + (size_t)(b * NH + h) * SEQ * HD;
    const u16* Vh = Vt + (size_t)(b * NH + h) * HD * SEQ;
    const float* kbh = kbt + h * SEQ;

    const int qrow = q0 + wave * 16 + l16;
    const bf16x8 qf0 = *(const bf16x8*)(Qh + (size_t)qrow * HD + quad * 8);
    const bf16x8 qf1 = *(const bf16x8*)(Qh + (size_t)qrow * HD + 32 + quad * 8);

    // staging lane map: 8 rows x 8 chunks per issue
    const int srow = lane >> 3;                       // 0..7
    const int scol = ((lane & 7) ^ srow) * 8;         // swizzled chunk (u16 off)
    const u16* Kg0 = Kh + (size_t)(wave*16 + srow)     * HD + scol;
    const u16* Kg1 = Kh + (size_t)(wave*16 + 8 + srow) * HD + scol;
    const u16* Vg0 = Vh + (size_t)(wave*16 + srow)     * SEQ + scol;
    const u16* Vg1 = Vh + (size_t)(wave*16 + 8 + srow) * SEQ + scol;
    // frag read swizzle: row&7 == l16&7
    const int sw = (quad ^ (l16 & 7)) * 8;            // d/key chunk 0..3
    // second half chunk offset = sw ^ 32

    float l_part[4] = {0.f, 0.f, 0.f, 0.f};
    f32x4 o[4];
#pragma unroll
    for (int j = 0; j < 4; ++j) o[j] = (f32x4){0.f,0.f,0.f,0.f};

    for (int kt = 0; kt < SEQ / 64; ++kt) {
        const int k0 = kt * 64;
        __syncthreads();                   // prior tile's frag reads done
        gload16((lptr_t)&Ks[wave*16][0],     Kg0 + (size_t)k0 * HD);
        gload16((lptr_t)&Ks[wave*16 + 8][0], Kg1 + (size_t)k0 * HD);
        gload16((lptr_t)&Vs[wave*16][0],     Vg0 + k0);
        gload16((lptr_t)&Vs[wave*16 + 8][0], Vg1 + k0);
        int dq = q0 - k0; if (dq < 0) dq = -dq;
        const int lo = (dq <= 63) ? 0 : dq - 63;
        if (tid < 128) {
            int idx = lo + tid;
            bs_[tid] = kbh[idx < SEQ ? idx : SEQ - 1];
        }
        __syncthreads();

        // ---- scores: QK^T ----
        f32x4 sc[4];
#pragma unroll
        for (int j = 0; j < 4; ++j) {
            bf16x8 kf0 = *(const bf16x8*)&Ks[j*16 + l16][sw];
            bf16x8 kf1 = *(const bf16x8*)&Ks[j*16 + l16][sw ^ 32];
            f32x4 z = (f32x4){0.f,0.f,0.f,0.f};
            z = __builtin_amdgcn_mfma_f32_16x16x32_bf16(qf0, kf0, z, 0, 0, 0);
            sc[j] = __builtin_amdgcn_mfma_f32_16x16x32_bf16(qf1, kf1, z, 0, 0, 0);
        }

        // ---- bias + exp (fixed max), accumulate per-lane l ----
#pragma unroll
        for (int r = 0; r < 4; ++r) {
            const int qidx = q0 + wave * 16 + quad * 4 + r;
            float e[4];
#pragma unroll
            for (int j = 0; j < 4; ++j) {
                int kidx = k0 + j * 16 + l16;
                int dist = qidx - kidx; if (dist < 0) dist = -dist;
                e[j] = __expf(sc[j][r] + bs_[dist - lo]);
                Ps[wave*16 + quad*4 + r][j*16 + l16] = f2bf(e[j]);
            }
            l_part[r] += (e[0] + e[1]) + (e[2] + e[3]);
        }
        // Ps wave-private: same-wave DS ordering suffices, no barrier.

        // ---- PV ----
        bf16x8 pf0 = *(const bf16x8*)&Ps[wave*16 + l16][quad*8];
        bf16x8 pf1 = *(const bf16x8*)&Ps[wave*16 + l16][32 + quad*8];
#pragma unroll
        for (int j = 0; j < 4; ++j) {
            bf16x8 vf0 = *(const bf16x8*)&Vs[j*16 + l16][sw];
            bf16x8 vf1 = *(const bf16x8*)&Vs[j*16 + l16][sw ^ 32];
            o[j] = __builtin_amdgcn_mfma_f32_16x16x32_bf16(pf0, vf0, o[j], 0, 0, 0);
            o[j] = __builtin_amdgcn_mfma_f32_16x16x32_bf16(pf1, vf1, o[j], 0, 0, 0);
        }
    }

    // ---- epilogue: reduce l across the 16 col-lanes, normalize, store ----
#pragma unroll
    for (int r = 0; r < 4; ++r) {
#pragma unroll
        for (int off = 1; off < 16; off <<= 1)
            l_part[r] += __shfl_xor(l_part[r], off);
        float inv = 1.0f / l_part[r];
        int row = q0 + wave * 16 + quad * 4 + r;
        u16* dst = attn_bf + (size_t)(b * SEQ + row) * DMODEL + h * HD;
#pragma unroll
        for (int j = 0; j < 4; ++j)
            dst[j*16 + l16] = f2bf(o[j][r] * inv);
    }
}

// ---------------------------------------------------------------------------
extern "C" void kernel_launch(void* const* d_in, const int* in_sizes, int n_in,
                              void* d_out, int out_size, void* d_ws, size_t ws_size,
                              hipStream_t stream)
{
    (void)in_sizes; (void)n_in; (void)out_size; (void)ws_size;
    const float* x      = (const float*)d_in[0];
    const float* qkv_w  = (const float*)d_in[1];
    const float* out_w  = (const float*)d_in[2];
    const float* bias_p = (const float*)d_in[3];
    const float* bias_a = (const float*)d_in[4];
    const float* freqs  = (const float*)d_in[5];
    float* out = (float*)d_out;

    // ws layout (bytes):
    //   [0, 24M)      qkv_bf [4096][3072] bf16   (attn_bf aliases [0,8M))
    //   [24M, 32M)    x_bf   [4096][1024] bf16   (Qb aliases after gemm1)
    //   [32M, 38M)    w1_bf  [3072][1024] bf16
    //   [38M, 40M)    w2_bf  [1024][1024] bf16
    //   [40M, 48M)    Kb     [2][16][2048][64] bf16
    //   [48M, 56M)    Vt     [2][16][64][2048] bf16
    //   [56M, +128K)  kbt    [16][2048] f32
    //   [+128K,+640K) cs_tab [2048][32][2] f32
    char* ws = (char*)d_ws;
    u16*   qkv_bf  = (u16*)ws;
    u16*   attn_bf = (u16*)ws;
    u16*   x_bf    = (u16*)(ws + 25165824);
    u16*   Qb      = x_bf;
    u16*   w1_bf   = (u16*)(ws + 33554432);
    u16*   w2_bf   = (u16*)(ws + 39845888);
    u16*   Kb      = (u16*)(ws + 41943040);
    u16*   Vt      = (u16*)(ws + 50331648);
    float* kbt     = (float*)(ws + 58720256);
    float* cs_tab  = (float*)(ws + 58720256 + 131072);

    f2bf_kernel<<<dim3(ROWS*DMODEL/1024), 256, 0, stream>>>(x, x_bf, ROWS*DMODEL);
    f2bf_kernel<<<dim3(NQKV*DMODEL/1024), 256, 0, stream>>>(qkv_w, w1_bf, NQKV*DMODEL);
    f2bf_kernel<<<dim3(DMODEL*DMODEL/1024), 256, 0, stream>>>(out_w, w2_bf, DMODEL*DMODEL);
    rope_table_kernel<<<dim3(SEQ*32/256), 256, 0, stream>>>(freqs, cs_tab);
    bias_table_kernel<<<dim3(NH*SEQ/256), 256, 0, stream>>>(bias_p, bias_a, kbt);

    gemm_bf16<true><<<dim3(ROWS/128, NQKV/128), 256, 0, stream>>>(x_bf, w1_bf, qkv_bf, ROWS, NQKV, DMODEL);
    qkv_convert<<<dim3(SEQ/64, NH, BATCH), 256, 0, stream>>>(qkv_bf, cs_tab, Qb, Kb, Vt);
    attn_mfma<<<dim3(SEQ/64, NH, BATCH), 256, 0, stream>>>(Qb, Kb, Vt, kbt, attn_bf);
    gemm_bf16<false><<<dim3(ROWS/128, DMODEL/128), 256, 0, stream>>>(attn_bf, w2_bf, out, ROWS, DMODEL, DMODEL);
}